// Round 4
// baseline (560.280 us; speedup 1.0000x reference)
//
#include <hip/hip_runtime.h>
#include <hip/hip_bf16.h>
#include <cstdint>
#include <cstddef>

// Problem constants (B, S, INP, HID) from the reference
#define B_   64
#define S_   2048
#define INP_ 512
#define HID_ 512
#define STILE 32         // s-rows per att_gemm block
#define NCH_ 64          // s-tiles per row (= S_/STILE = att_gemm grid.x)

typedef float          floatx4  __attribute__((ext_vector_type(4)));
typedef __bf16         bf16x8   __attribute__((ext_vector_type(8)));
typedef unsigned short ushortx8 __attribute__((ext_vector_type(8)));
typedef unsigned short ushortx4 __attribute__((ext_vector_type(4)));

#define K2E 1.4426950408889634f

__device__ __forceinline__ unsigned short f2bf(float f) {
  unsigned u = __float_as_uint(f);
  u += 0x7FFFu + ((u >> 16) & 1u);          // round-to-nearest-even
  return (unsigned short)(u >> 16);
}
__device__ __forceinline__ float bf2f(unsigned short h) {
  return __uint_as_float(((unsigned)h) << 16);
}
// tanh(x) = 1 - 2/(exp(2x)+1); exp(2x) = exp2(x * 2*log2(e)).  ~1e-6 accuracy, inf-safe.
__device__ __forceinline__ float fast_tanh(float x) {
  float u = __builtin_amdgcn_exp2f(x * 2.88539008177792681472f);
  return 1.0f - 2.0f * __builtin_amdgcn_rcpf(u + 1.0f);
}

// mask-encoding autodetect shared logic: returns 0=int32, 1=float32, 2=uint8
__device__ __forceinline__ int detect_mask_mode(const void* mask, int t, int* flags) {
  if (t == 0) *flags = 0;
  __syncthreads();
  int f = 0;
  const unsigned* mw = (const unsigned*)mask;
  for (int i = t; i < 512; i += 256) {
    unsigned v = mw[i];
    if (v > 1u) f |= 1;
    if (v != 0u && v != 0x3f800000u) f |= 2;
  }
  if (f) atomicOr(flags, f);
  __syncthreads();
  const int fl = *flags;
  return ((fl & 1) == 0) ? 0 : (((fl & 2) == 0) ? 1 : 2);
}
__device__ __forceinline__ bool mask_at(const void* mask, int mode, size_t idx) {
  if (mode == 0) return ((const int*)mask)[idx] != 0;
  if (mode == 1) return ((const float*)mask)[idx] != 0.0f;
  return ((const unsigned char*)mask)[idx] != 0;
}

// ---------------------------------------------------------------------------
// prep: blocks [0,128): pack Wc -> bf16 MFMA A-fragment order.
//       blocks [128,640): hid[b,h] = inp[b,:]·Wl[h,:] + bl[h].
// pk[(m16*1024 + ks*64 + lane)*8 + j] = Wc[m16*16 + (lane&15)][ks*32 + (lane>>4)*8 + j]
// ---------------------------------------------------------------------------
__global__ __launch_bounds__(256) void prep_kernel(
    const float* __restrict__ inp, const float* __restrict__ Wl,
    const float* __restrict__ bl, float* __restrict__ hid,
    const float* __restrict__ Wc, unsigned short* __restrict__ pk)
{
  __shared__ float vs[512];
  const int t = threadIdx.x;
  if (blockIdx.x < 128) {
    int g = blockIdx.x * 256 + t;               // 32768 threads
    int l = g & 63, ks = (g >> 6) & 15, m16 = g >> 10;
    int row = m16 * 16 + (l & 15);
    int kb  = ks * 32 + (l >> 4) * 8;
    const float4* s = (const float4*)(Wc + (size_t)row * 512 + kb);
    float4 a = s[0], c = s[1];
    ushortx8 o = { f2bf(a.x), f2bf(a.y), f2bf(a.z), f2bf(a.w),
                   f2bf(c.x), f2bf(c.y), f2bf(c.z), f2bf(c.w) };
    *(ushortx8*)(pk + (size_t)g * 8) = o;
    return;
  }
  const int bx = blockIdx.x - 128;              // 0..511
  const int xo = bx & 7, b = bx >> 3;
  const int w = t >> 6, lane = t & 63;
  for (int i = t; i < 512; i += 256) vs[i] = inp[(size_t)b * 512 + i];
  __syncthreads();
  float vl[8];
  #pragma unroll
  for (int j = 0; j < 8; ++j) vl[j] = vs[lane * 8 + j];
  const int h0 = xo * 64 + w * 16;
  #pragma unroll
  for (int i = 0; i < 16; ++i) {
    const int h = h0 + i;
    const float4* wr = (const float4*)(Wl + (size_t)h * 512 + lane * 8);
    float4 w0 = wr[0], w1 = wr[1];
    float d = w0.x*vl[0] + w0.y*vl[1] + w0.z*vl[2] + w0.w*vl[3]
            + w1.x*vl[4] + w1.y*vl[5] + w1.z*vl[6] + w1.w*vl[7];
    #pragma unroll
    for (int off = 32; off; off >>= 1) d += __shfl_xor(d, off);
    if (lane == 0) hid[(size_t)b * 512 + h] = bl[h] + d;
  }
}

// ---------------------------------------------------------------------------
// att GEMM + tile-softmax partials.  s-tile 32, 4 waves x 128 h (m=8, n=2),
// acc = 64 AGPRs -> register headroom for T14 software pipelining:
// the persistent [32][512] tile's phase-slices are DISJOINT, so slice p+1 is
// staged (loads issued before MFMA(p), LDS writes after) with ONE barrier per
// phase — HBM latency hides under MFMA instead of draining at a barrier.
// ---------------------------------------------------------------------------
__global__ __launch_bounds__(256, 3) void att_gemm_kernel(
    const float* __restrict__ context, const unsigned short* __restrict__ Wc_pk,
    const float* __restrict__ hid, const float* __restrict__ bc,
    const float* __restrict__ V, const void* __restrict__ mask,
    float* __restrict__ att, float* __restrict__ partial,
    float* __restrict__ mt, float* __restrict__ lt)
{
  // context tile: 32 s-rows x 512 k (bf16), per-128-col-slice XOR swizzle
  __shared__ alignas(16) unsigned short bsm[STILE * 512];   // 32 KB
  __shared__ float hid_sm[512];
  __shared__ float V_sm[512];
  __shared__ float bc_sm[512];
  __shared__ float att_sm[STILE];
  __shared__ float w_sm[STILE];
  __shared__ int   flags;

  const int b    = blockIdx.y;
  const int c    = blockIdx.x;
  const int s0   = c * STILE;
  const int t    = threadIdx.x;
  const int lane = t & 63;
  const int w    = t >> 6;          // wave id: h-rows [w*128, w*128+128)
  const int quad = lane >> 4;
  const int l15  = lane & 15;

  const int mode = detect_mask_mode(mask, t, &flags);   // has 2 syncthreads

  for (int i = t; i < 512; i += 256) {
    hid_sm[i] = hid[b * 512 + i];
    V_sm[i]   = V[i];
    bc_sm[i]  = bc[i];
  }
  if (t < STILE) att_sm[t] = 0.0f;

  floatx4 acc[8][2];
  #pragma unroll
  for (int m = 0; m < 8; ++m)
    #pragma unroll
    for (int n = 0; n < 2; ++n) { floatx4 z = {0.f,0.f,0.f,0.f}; acc[m][n] = z; }

  const unsigned short* apBase = Wc_pk + (size_t)(w * 8) * 8192 + lane * 8;
  const float* src = context + ((size_t)b * S_ + s0) * INP_;

  // per-thread staging geometry: 4 float4 per phase
  // id = t + i*256 -> row = (t>>5) + i*8 (i<4), c4 = t&31 (constant)
  const int srow = t >> 5;                // base row
  const int c4   = t & 31;
  const int half = c4 & 1;
  // swizzled chunk per thread (row&7 = srow&7, invariant under +8)
  const int sw   = (c4 >> 1) ^ (srow & 7);
  const int dst_off = sw * 8 + half * 4;  // within-slice ushort offset

  // ---- prologue: stage slice 0
  {
    float4 stg[4];
    #pragma unroll
    for (int i = 0; i < 4; ++i)
      stg[i] = *(const float4*)(src + (size_t)(srow + i * 8) * INP_ + c4 * 4);
    #pragma unroll
    for (int i = 0; i < 4; ++i) {
      ushortx4 hv = { f2bf(stg[i].x), f2bf(stg[i].y), f2bf(stg[i].z), f2bf(stg[i].w) };
      *(ushortx4*)(&bsm[(srow + i * 8) * 512 + dst_off]) = hv;
    }
  }
  __syncthreads();

  #pragma unroll
  for (int phase = 0; phase < 4; ++phase) {
    // T14 issue-early: loads for slice phase+1 go out before the MFMAs
    float4 nst[4];
    if (phase < 3) {
      #pragma unroll
      for (int i = 0; i < 4; ++i)
        nst[i] = *(const float4*)(src + (size_t)(srow + i * 8) * INP_
                                      + (phase + 1) * 128 + c4 * 4);
    }
    // MFMA on slice `phase`
    #pragma unroll
    for (int ksl = 0; ksl < 4; ++ksl) {
      const int ksg = phase * 4 + ksl;
      bf16x8 bfr[2];
      #pragma unroll
      for (int n = 0; n < 2; ++n) {
        int row = n * 16 + l15;
        int cc  = ksl * 4 + quad;
        bfr[n] = *(const bf16x8*)(&bsm[row * 512 + phase * 128 + ((cc ^ (row & 7)) * 8)]);
      }
      #pragma unroll
      for (int m = 0; m < 8; ++m) {
        bf16x8 af = *(const bf16x8*)(apBase + (size_t)m * 8192 + ksg * 512);
        acc[m][0] = __builtin_amdgcn_mfma_f32_16x16x32_bf16(af, bfr[0], acc[m][0], 0, 0, 0);
        acc[m][1] = __builtin_amdgcn_mfma_f32_16x16x32_bf16(af, bfr[1], acc[m][1], 0, 0, 0);
      }
    }
    // T14 write-late: convert + LDS-write slice phase+1 (disjoint region)
    if (phase < 3) {
      #pragma unroll
      for (int i = 0; i < 4; ++i) {
        ushortx4 hv = { f2bf(nst[i].x), f2bf(nst[i].y), f2bf(nst[i].z), f2bf(nst[i].w) };
        *(ushortx4*)(&bsm[(srow + i * 8) * 512 + (phase + 1) * 128 + dst_off]) = hv;
      }
    }
    __syncthreads();
  }

  // ---- att epilogue.  C/D layout (m89-verified): col(s)=lane&15, row(h)=quad*4+reg.
  float attacc[2] = {0.f, 0.f};
  #pragma unroll
  for (int m = 0; m < 8; ++m) {
    const int hb = w * 128 + m * 16 + quad * 4;
    #pragma unroll
    for (int r = 0; r < 4; ++r) {
      const int h = hb + r;
      const float base = hid_sm[h] + bc_sm[h];
      const float vv = V_sm[h];
      #pragma unroll
      for (int n = 0; n < 2; ++n)
        attacc[n] += vv * fast_tanh(base + acc[m][n][r]);
    }
  }
  #pragma unroll
  for (int n = 0; n < 2; ++n) {
    float v = attacc[n];
    v += __shfl_xor(v, 16);
    v += __shfl_xor(v, 32);
    if (lane < 16) atomicAdd(&att_sm[n * 16 + l15], v);
  }
  __syncthreads();

  // ---- tile softmax: m_c, w_s, l_c (threads 0..31 = lanes 0..31 of wave 0)
  if (t < STILE) {
    att[(size_t)b * S_ + s0 + t] = att_sm[t];
    const bool m = mask_at(mask, mode, (size_t)b * S_ + s0 + t);
    const float av = att_sm[t];
    float mv = m ? -1e30f : av;
    #pragma unroll
    for (int off = 16; off; off >>= 1) mv = fmaxf(mv, __shfl_xor(mv, off));
    const float wv = m ? 0.0f : __builtin_amdgcn_exp2f((av - mv) * K2E);
    w_sm[t] = wv;
    float lv = wv;
    #pragma unroll
    for (int off = 16; off; off >>= 1) lv += __shfl_xor(lv, off);
    if (t == 0) { mt[b * NCH_ + c] = mv; lt[b * NCH_ + c] = lv; }
  }
  __syncthreads();

  // ---- weighted tile reduction: partial_c[k] = sum_s w_s * ctx_tile[s,k]
  // thread owns k = {2t, 2t+1}; swizzle XORs bits 3-5 of the element index.
  {
    const int k0 = t * 2;
    float ax = 0.f, ay = 0.f;
    #pragma unroll 8
    for (int s = 0; s < STILE; ++s) {
      const unsigned v = *(const unsigned*)(&bsm[s * 512 + (k0 ^ ((s & 7) << 3))]);
      const float wv = w_sm[s];
      ax = fmaf(wv, bf2f((unsigned short)(v & 0xffffu)), ax);
      ay = fmaf(wv, bf2f((unsigned short)(v >> 16)), ay);
    }
    float2 o; o.x = ax; o.y = ay;
    *(float2*)(partial + ((size_t)c * B_ + b) * INP_ + k0) = o;
  }
}

// ---------------------------------------------------------------------------
// finalize: per b, combine tile (m_c, l_c) -> global (M, L); write alpha and
// the per-tile rescale sc[c] = e^(m_c - M) / L.
// ---------------------------------------------------------------------------
__global__ __launch_bounds__(256) void finalize_kernel(
    const void* __restrict__ mask, const float* __restrict__ att,
    const float* __restrict__ mt, const float* __restrict__ lt,
    float* __restrict__ sc, float* __restrict__ alpha)
{
  __shared__ int flags;
  __shared__ float Msh, Lsh;
  const int b = blockIdx.x, t = threadIdx.x;
  const int mode = detect_mask_mode(mask, t, &flags);

  if (t < NCH_) {                               // NCH_ = 64 = one full wave
    float m = mt[b * NCH_ + t];
    #pragma unroll
    for (int off = 32; off; off >>= 1) m = fmaxf(m, __shfl_xor(m, off));
    float e = __builtin_amdgcn_exp2f((mt[b * NCH_ + t] - m) * K2E) * lt[b * NCH_ + t];
    #pragma unroll
    for (int off = 32; off; off >>= 1) e += __shfl_xor(e, off);
    if (t == 0) { Msh = m; Lsh = e; }
  }
  __syncthreads();
  const float M = Msh;
  const float rL = 1.0f / Lsh;
  if (t < NCH_) sc[b * NCH_ + t] = __builtin_amdgcn_exp2f((mt[b * NCH_ + t] - M) * K2E) * rL;

  #pragma unroll
  for (int i = 0; i < 8; ++i) {
    const int idx = i * 256 + t;
    const bool m = mask_at(mask, mode, (size_t)b * S_ + idx);
    const float a = m ? 0.0f
                      : __builtin_amdgcn_exp2f((att[(size_t)b * S_ + idx] - M) * K2E) * rL;
    alpha[(size_t)b * S_ + idx] = a;
  }
}

// ---------------------------------------------------------------------------
// hidden[b,h] = bc[h] + Wc[h,:] · cbar[b,:],  cbar = sum_c sc[c]*partial[c][b]
// ---------------------------------------------------------------------------
__global__ __launch_bounds__(256) void hiddendot_kernel(
    const float* __restrict__ Wc, const float* __restrict__ bc,
    const float* __restrict__ partial, const float* __restrict__ sc,
    float* __restrict__ hidden)
{
  __shared__ float vs[512];
  __shared__ float scs[NCH_];
  const int b = blockIdx.y, t = threadIdx.x;
  const int w = t >> 6, lane = t & 63;
  if (t < NCH_) scs[t] = sc[b * NCH_ + t];
  __syncthreads();
  for (int i = t; i < 512; i += 256) {
    float s = 0.0f;
    #pragma unroll 4
    for (int c = 0; c < NCH_; ++c)
      s += scs[c] * partial[((size_t)c * B_ + b) * INP_ + i];
    vs[i] = s;
  }
  __syncthreads();
  float vl[8];
  #pragma unroll
  for (int j = 0; j < 8; ++j) vl[j] = vs[lane * 8 + j];
  const int h0 = blockIdx.x * 64 + w * 16;
  #pragma unroll
  for (int i = 0; i < 16; ++i) {
    const int h = h0 + i;
    const float4* wr = (const float4*)(Wc + (size_t)h * 512 + lane * 8);
    float4 w0 = wr[0], w1 = wr[1];
    float d = w0.x*vl[0] + w0.y*vl[1] + w0.z*vl[2] + w0.w*vl[3]
            + w1.x*vl[4] + w1.y*vl[5] + w1.z*vl[6] + w1.w*vl[7];
    #pragma unroll
    for (int off = 32; off; off >>= 1) d += __shfl_xor(d, off);
    if (lane == 0) hidden[(size_t)b * 512 + h] = bc[h] + d;
  }
}

// ---------------------------------------------------------------------------
extern "C" void kernel_launch(void* const* d_in, const int* in_sizes, int n_in,
                              void* d_out, int out_size, void* d_ws, size_t ws_size,
                              hipStream_t stream)
{
  const float* inp     = (const float*)d_in[0];
  const float* context = (const float*)d_in[1];
  const void*  mask    = d_in[2];
  const float* Wl      = (const float*)d_in[3];
  const float* bl      = (const float*)d_in[4];
  const float* Wc      = (const float*)d_in[5];
  const float* bc      = (const float*)d_in[6];
  const float* V       = (const float*)d_in[7];

  float* hidden = (float*)d_out;                 // [B, HID]
  float* alpha  = (float*)d_out + B_ * HID_;     // [B, S]

  char* ws = (char*)d_ws;
  const size_t HIDW = (size_t)B_ * HID_ * 4;           // 128 KB
  const size_t ATT  = (size_t)B_ * S_ * 4;             // 512 KB
  const size_t PK   = (size_t)HID_ * INP_ * 2;         // 512 KB
  const size_t PART = (size_t)NCH_ * B_ * INP_ * 4;    // 8 MB
  const size_t MT   = (size_t)B_ * NCH_ * 4;           // 16 KB

  float* hid_ws      = (float*)ws;
  float* att_ws      = (float*)(ws + HIDW);
  unsigned short* pk = (unsigned short*)(ws + HIDW + ATT);
  float* partial     = (float*)(ws + HIDW + ATT + PK);
  float* mt          = (float*)(ws + HIDW + ATT + PK + PART);
  float* lt          = (float*)(ws + HIDW + ATT + PK + PART + MT);
  float* sc          = (float*)(ws + HIDW + ATT + PK + PART + 2 * MT);

  prep_kernel<<<640, 256, 0, stream>>>(inp, Wl, bl, hid_ws, Wc, pk);
  att_gemm_kernel<<<dim3(NCH_, B_), 256, 0, stream>>>(
      context, pk, hid_ws, bc, V, mask, att_ws, partial, mt, lt);
  finalize_kernel<<<B_, 256, 0, stream>>>(mask, att_ws, mt, lt, sc, alpha);
  hiddendot_kernel<<<dim3(HID_ / 64, B_), 256, 0, stream>>>(Wc, bc, partial, sc, hidden);
}

// Round 5
// 479.103 us; speedup vs baseline: 1.1694x; 1.1694x over previous
//
#include <hip/hip_runtime.h>
#include <hip/hip_bf16.h>
#include <cstdint>
#include <cstddef>

// Problem constants (B, S, INP, HID) from the reference
#define B_   64
#define S_   2048
#define INP_ 512
#define HID_ 512
#define STILE 64         // s-rows per att_gemm block
#define NCH_ 32          // s-tiles per row (= S_/STILE = att_gemm grid.x)

typedef float          floatx4  __attribute__((ext_vector_type(4)));
typedef __bf16         bf16x8   __attribute__((ext_vector_type(8)));
typedef unsigned short ushortx8 __attribute__((ext_vector_type(8)));
typedef unsigned short ushortx4 __attribute__((ext_vector_type(4)));

#define K2E 1.4426950408889634f

__device__ __forceinline__ unsigned short f2bf(float f) {
  unsigned u = __float_as_uint(f);
  u += 0x7FFFu + ((u >> 16) & 1u);          // round-to-nearest-even
  return (unsigned short)(u >> 16);
}
__device__ __forceinline__ float bf2f(unsigned short h) {
  return __uint_as_float(((unsigned)h) << 16);
}
// tanh(x) = 1 - 2/(exp(2x)+1); exp(2x) = exp2(x * 2*log2(e)).  ~1e-6 accuracy, inf-safe.
__device__ __forceinline__ float fast_tanh(float x) {
  float u = __builtin_amdgcn_exp2f(x * 2.88539008177792681472f);
  return 1.0f - 2.0f * __builtin_amdgcn_rcpf(u + 1.0f);
}

__device__ __forceinline__ bool mask_at(const void* mask, int mode, size_t idx) {
  if (mode == 0) return ((const int*)mask)[idx] != 0;
  if (mode == 1) return ((const float*)mask)[idx] != 0.0f;
  return ((const unsigned char*)mask)[idx] != 0;
}

// ---------------------------------------------------------------------------
// prep: blocks [0,128): pack Wc -> bf16 MFMA A-fragment order.
//       blocks [128,640): hid[b,h] = inp[b,:]·Wl[h,:] + bl[h].
//       block 640: mask-encoding autodetect -> mode_ws (hoisted out of the
//       2048 att_gemm blocks; they read it as one uniform scalar).
// pk[(m16*1024 + ks*64 + lane)*8 + j] = Wc[m16*16 + (lane&15)][ks*32 + (lane>>4)*8 + j]
// ---------------------------------------------------------------------------
__global__ __launch_bounds__(256) void prep_kernel(
    const float* __restrict__ inp, const float* __restrict__ Wl,
    const float* __restrict__ bl, float* __restrict__ hid,
    const float* __restrict__ Wc, unsigned short* __restrict__ pk,
    const void* __restrict__ mask, int* __restrict__ mode_ws)
{
  __shared__ float vs[512];
  __shared__ int flags;
  const int t = threadIdx.x;
  if (blockIdx.x == 640) {
    // mask autodetect: 0=int32 0/1, 1=float32 0.0/1.0, 2=uint8
    if (t == 0) flags = 0;
    __syncthreads();
    int f = 0;
    const unsigned* mw = (const unsigned*)mask;
    for (int i = t; i < 512; i += 256) {
      unsigned v = mw[i];
      if (v > 1u) f |= 1;
      if (v != 0u && v != 0x3f800000u) f |= 2;
    }
    if (f) atomicOr(&flags, f);
    __syncthreads();
    if (t == 0) {
      const int fl = flags;
      *mode_ws = ((fl & 1) == 0) ? 0 : (((fl & 2) == 0) ? 1 : 2);
    }
    return;
  }
  if (blockIdx.x < 128) {
    int g = blockIdx.x * 256 + t;               // 32768 threads
    int l = g & 63, ks = (g >> 6) & 15, m16 = g >> 10;
    int row = m16 * 16 + (l & 15);
    int kb  = ks * 32 + (l >> 4) * 8;
    const float4* s = (const float4*)(Wc + (size_t)row * 512 + kb);
    float4 a = s[0], c = s[1];
    ushortx8 o = { f2bf(a.x), f2bf(a.y), f2bf(a.z), f2bf(a.w),
                   f2bf(c.x), f2bf(c.y), f2bf(c.z), f2bf(c.w) };
    *(ushortx8*)(pk + (size_t)g * 8) = o;
    return;
  }
  const int bx = blockIdx.x - 128;              // 0..511
  const int xo = bx & 7, b = bx >> 3;
  const int w = t >> 6, lane = t & 63;
  for (int i = t; i < 512; i += 256) vs[i] = inp[(size_t)b * 512 + i];
  __syncthreads();
  float vl[8];
  #pragma unroll
  for (int j = 0; j < 8; ++j) vl[j] = vs[lane * 8 + j];
  const int h0 = xo * 64 + w * 16;
  #pragma unroll
  for (int i = 0; i < 16; ++i) {
    const int h = h0 + i;
    const float4* wr = (const float4*)(Wl + (size_t)h * 512 + lane * 8);
    float4 w0 = wr[0], w1 = wr[1];
    float d = w0.x*vl[0] + w0.y*vl[1] + w0.z*vl[2] + w0.w*vl[3]
            + w1.x*vl[4] + w1.y*vl[5] + w1.z*vl[6] + w1.w*vl[7];
    #pragma unroll
    for (int off = 32; off; off >>= 1) d += __shfl_xor(d, off);
    if (lane == 0) hid[(size_t)b * 512 + h] = bl[h] + d;
  }
}

// ---------------------------------------------------------------------------
// att GEMM + tile-softmax partials (flash-style; round-0 proven MFMA core).
// Per (s-tile c, b): ctx[h,s] = sum_k Wc[h,k]*context[b,s,k] (bf16 MFMA);
// att[b,s] = sum_h V[h]*tanh(hid+ctx+bc); then tile-local softmax partials
// from the persistent [64][512] bf16 tile (no second context pass).
//
// Round-5 change: the tile's phase column-slices are DISJOINT, so the
// per-phase WAR barrier is redundant.  Loop is now
//   { stage slice p+1 ; MFMA slice p ; barrier }   (ONE barrier per phase)
// which lets each wave's HBM staging stall overlap other waves' MFMAs.
// setprio(1) wraps the pure-MFMA cluster (T5; 2 desynced blocks/CU = role
// diversity regime where it measured +4-7%).
// ---------------------------------------------------------------------------
__global__ __launch_bounds__(256, 2) void att_gemm_kernel(
    const float* __restrict__ context, const unsigned short* __restrict__ Wc_pk,
    const float* __restrict__ hid, const float* __restrict__ bc,
    const float* __restrict__ V, const void* __restrict__ mask,
    const int* __restrict__ mode_ws,
    float* __restrict__ att, float* __restrict__ partial,
    float* __restrict__ mt, float* __restrict__ lt)
{
  // full context tile: 64 s-rows x 512 k (bf16), per-128-col-slice XOR swizzle
  __shared__ alignas(16) unsigned short bsm[STILE * 512];   // 64 KB
  __shared__ float hid_sm[512];
  __shared__ float V_sm[512];
  __shared__ float bc_sm[512];
  __shared__ float att_sm[STILE];
  __shared__ float w_sm[STILE];

  const int b    = blockIdx.y;
  const int c    = blockIdx.x;
  const int s0   = c * STILE;
  const int t    = threadIdx.x;
  const int lane = t & 63;
  const int w    = t >> 6;          // wave id: h-rows [w*128, w*128+128)
  const int quad = lane >> 4;
  const int l15  = lane & 15;

  const int mode = *mode_ws;        // uniform scalar (prep_kernel wrote it)

  for (int i = t; i < 512; i += 256) {
    hid_sm[i] = hid[b * 512 + i];
    V_sm[i]   = V[i];
    bc_sm[i]  = bc[i];
  }
  if (t < STILE) att_sm[t] = 0.0f;

  floatx4 acc[8][4];
  #pragma unroll
  for (int m = 0; m < 8; ++m)
    #pragma unroll
    for (int n = 0; n < 4; ++n) { floatx4 z = {0.f,0.f,0.f,0.f}; acc[m][n] = z; }

  const unsigned short* apBase = Wc_pk + (size_t)(w * 8) * 8192 + lane * 8;
  const float* src = context + ((size_t)b * S_ + s0) * INP_;

  // staging: 8 float4 per thread per phase; synchronous (load->cvt->ds_write)
  // so no register lifetime crosses the MFMA section (248/256 budget).
  auto stage = [&](int p) {
    #pragma unroll
    for (int i = 0; i < 8; ++i) {
      int id  = t + i * 256;                  // 0..2047, 32 float4-chunks per row
      int row = id >> 5;
      int c4  = id & 31;
      float4 f = *(const float4*)(src + (size_t)row * INP_ + p * 128 + c4 * 4);
      int chunk = c4 >> 1, half = c4 & 1;
      int sw = chunk ^ (row & 7);
      ushortx4 hv = { f2bf(f.x), f2bf(f.y), f2bf(f.z), f2bf(f.w) };
      *(ushortx4*)(&bsm[row * 512 + p * 128 + sw * 8 + half * 4]) = hv;
    }
  };

  stage(0);
  __syncthreads();                            // slice 0 + params visible

  for (int phase = 0; phase < 4; ++phase) {
    if (phase < 3) stage(phase + 1);          // disjoint slice: no WAR barrier
    #pragma unroll
    for (int ksl = 0; ksl < 4; ++ksl) {
      const int ksg = phase * 4 + ksl;
      bf16x8 af[8];
      #pragma unroll
      for (int m = 0; m < 8; ++m)
        af[m] = *(const bf16x8*)(apBase + (size_t)m * 8192 + ksg * 512);
      bf16x8 bfr[4];
      #pragma unroll
      for (int n = 0; n < 4; ++n) {
        int row = n * 16 + l15;
        int cc  = ksl * 4 + quad;
        bfr[n] = *(const bf16x8*)(&bsm[row * 512 + phase * 128 + ((cc ^ (row & 7)) * 8)]);
      }
      __builtin_amdgcn_s_setprio(1);
      #pragma unroll
      for (int m = 0; m < 8; ++m)
        #pragma unroll
        for (int n = 0; n < 4; ++n)
          acc[m][n] = __builtin_amdgcn_mfma_f32_16x16x32_bf16(af[m], bfr[n], acc[m][n], 0, 0, 0);
      __builtin_amdgcn_s_setprio(0);
    }
    __syncthreads();                          // slice phase+1 visible for next iter
  }

  // ---- att epilogue.  C/D layout (m89-verified): col(s)=lane&15, row(h)=quad*4+reg.
  float attacc[4] = {0.f, 0.f, 0.f, 0.f};
  #pragma unroll
  for (int m = 0; m < 8; ++m) {
    const int hb = w * 128 + m * 16 + quad * 4;
    #pragma unroll
    for (int r = 0; r < 4; ++r) {
      const int h = hb + r;
      const float base = hid_sm[h] + bc_sm[h];
      const float vv = V_sm[h];
      #pragma unroll
      for (int n = 0; n < 4; ++n)
        attacc[n] += vv * fast_tanh(base + acc[m][n][r]);
    }
  }
  #pragma unroll
  for (int n = 0; n < 4; ++n) {
    float v = attacc[n];
    v += __shfl_xor(v, 16);
    v += __shfl_xor(v, 32);
    if (lane < 16) atomicAdd(&att_sm[n * 16 + l15], v);
  }
  __syncthreads();

  // ---- tile softmax: m_c, w_s, l_c (threads 0..63 = wave 0)
  if (t < STILE) {
    att[(size_t)b * S_ + s0 + t] = att_sm[t];
    const bool m = mask_at(mask, mode, (size_t)b * S_ + s0 + t);
    const float av = att_sm[t];
    float mv = m ? -1e30f : av;
    #pragma unroll
    for (int off = 32; off; off >>= 1) mv = fmaxf(mv, __shfl_xor(mv, off));
    const float wv = m ? 0.0f : __builtin_amdgcn_exp2f((av - mv) * K2E);
    w_sm[t] = wv;
    float lv = wv;
    #pragma unroll
    for (int off = 32; off; off >>= 1) lv += __shfl_xor(lv, off);
    if (t == 0) { mt[b * NCH_ + c] = mv; lt[b * NCH_ + c] = lv; }
  }
  __syncthreads();

  // ---- weighted tile reduction: partial_c[k] = sum_s w_s * ctx_tile[s,k]
  // thread owns k = {2t, 2t+1}; LDS index = unswizzled ^ ((s&7)<<3).
  {
    const int k0 = t * 2;
    const int p  = k0 >> 7, kl = k0 & 127;
    const int c4 = kl >> 2, j = kl & 3;
    const int idxu = p * 128 + (c4 >> 1) * 8 + (c4 & 1) * 4 + j;
    float ax = 0.f, ay = 0.f;
    #pragma unroll 8
    for (int s = 0; s < STILE; ++s) {
      const unsigned v = *(const unsigned*)(&bsm[s * 512 + (idxu ^ ((s & 7) << 3))]);
      const float wv = w_sm[s];
      ax = fmaf(wv, bf2f((unsigned short)(v & 0xffffu)), ax);
      ay = fmaf(wv, bf2f((unsigned short)(v >> 16)), ay);
    }
    float2 o; o.x = ax; o.y = ay;
    *(float2*)(partial + ((size_t)c * B_ + b) * INP_ + k0) = o;
  }
}

// ---------------------------------------------------------------------------
// finalize: per b, combine tile (m_c, l_c) -> global (M, L); write alpha and
// the per-tile rescale sc[c] = e^(m_c - M) / L.
// ---------------------------------------------------------------------------
__global__ __launch_bounds__(256) void finalize_kernel(
    const void* __restrict__ mask, const float* __restrict__ att,
    const int* __restrict__ mode_ws,
    const float* __restrict__ mt, const float* __restrict__ lt,
    float* __restrict__ sc, float* __restrict__ alpha)
{
  __shared__ float Msh, Lsh;
  const int b = blockIdx.x, t = threadIdx.x;
  const int mode = *mode_ws;

  if (t < NCH_) {                               // NCH_ = 32: half-wave reduce
    float m = mt[b * NCH_ + t];
    #pragma unroll
    for (int off = 16; off; off >>= 1) m = fmaxf(m, __shfl_xor(m, off));
    float e = __builtin_amdgcn_exp2f((mt[b * NCH_ + t] - m) * K2E) * lt[b * NCH_ + t];
    #pragma unroll
    for (int off = 16; off; off >>= 1) e += __shfl_xor(e, off);
    if (t == 0) { Msh = m; Lsh = e; }
  }
  __syncthreads();
  const float M = Msh;
  const float rL = 1.0f / Lsh;
  if (t < NCH_) sc[b * NCH_ + t] = __builtin_amdgcn_exp2f((mt[b * NCH_ + t] - M) * K2E) * rL;

  #pragma unroll
  for (int i = 0; i < 8; ++i) {
    const int idx = i * 256 + t;
    const bool m = mask_at(mask, mode, (size_t)b * S_ + idx);
    const float a = m ? 0.0f
                      : __builtin_amdgcn_exp2f((att[(size_t)b * S_ + idx] - M) * K2E) * rL;
    alpha[(size_t)b * S_ + idx] = a;
  }
}

// ---------------------------------------------------------------------------
// hidden[b,h] = bc[h] + Wc[h,:] · cbar[b,:],  cbar = sum_c sc[c]*partial[c][b]
// ---------------------------------------------------------------------------
__global__ __launch_bounds__(256) void hiddendot_kernel(
    const float* __restrict__ Wc, const float* __restrict__ bc,
    const float* __restrict__ partial, const float* __restrict__ sc,
    float* __restrict__ hidden)
{
  __shared__ float vs[512];
  __shared__ float scs[NCH_];
  const int b = blockIdx.y, t = threadIdx.x;
  const int w = t >> 6, lane = t & 63;
  if (t < NCH_) scs[t] = sc[b * NCH_ + t];
  __syncthreads();
  for (int i = t; i < 512; i += 256) {
    float s = 0.0f;
    #pragma unroll 4
    for (int c = 0; c < NCH_; ++c)
      s += scs[c] * partial[((size_t)c * B_ + b) * INP_ + i];
    vs[i] = s;
  }
  __syncthreads();
  float vl[8];
  #pragma unroll
  for (int j = 0; j < 8; ++j) vl[j] = vs[lane * 8 + j];
  const int h0 = blockIdx.x * 64 + w * 16;
  #pragma unroll
  for (int i = 0; i < 16; ++i) {
    const int h = h0 + i;
    const float4* wr = (const float4*)(Wc + (size_t)h * 512 + lane * 8);
    float4 w0 = wr[0], w1 = wr[1];
    float d = w0.x*vl[0] + w0.y*vl[1] + w0.z*vl[2] + w0.w*vl[3]
            + w1.x*vl[4] + w1.y*vl[5] + w1.z*vl[6] + w1.w*vl[7];
    #pragma unroll
    for (int off = 32; off; off >>= 1) d += __shfl_xor(d, off);
    if (lane == 0) hidden[(size_t)b * 512 + h] = bc[h] + d;
  }
}

// ---------------------------------------------------------------------------
extern "C" void kernel_launch(void* const* d_in, const int* in_sizes, int n_in,
                              void* d_out, int out_size, void* d_ws, size_t ws_size,
                              hipStream_t stream)
{
  const float* inp     = (const float*)d_in[0];
  const float* context = (const float*)d_in[1];
  const void*  mask    = d_in[2];
  const float* Wl      = (const float*)d_in[3];
  const float* bl      = (const float*)d_in[4];
  const float* Wc      = (const float*)d_in[5];
  const float* bc      = (const float*)d_in[6];
  const float* V       = (const float*)d_in[7];

  float* hidden = (float*)d_out;                 // [B, HID]
  float* alpha  = (float*)d_out + B_ * HID_;     // [B, S]

  char* ws = (char*)d_ws;
  const size_t HIDW = (size_t)B_ * HID_ * 4;           // 128 KB
  const size_t ATT  = (size_t)B_ * S_ * 4;             // 512 KB
  const size_t PK   = (size_t)HID_ * INP_ * 2;         // 512 KB
  const size_t PART = (size_t)NCH_ * B_ * INP_ * 4;    // 4 MB
  const size_t MT   = (size_t)B_ * NCH_ * 4;           // 8 KB

  float* hid_ws      = (float*)ws;
  float* att_ws      = (float*)(ws + HIDW);
  unsigned short* pk = (unsigned short*)(ws + HIDW + ATT);
  float* partial     = (float*)(ws + HIDW + ATT + PK);
  float* mt          = (float*)(ws + HIDW + ATT + PK + PART);
  float* lt          = (float*)(ws + HIDW + ATT + PK + PART + MT);
  float* sc          = (float*)(ws + HIDW + ATT + PK + PART + 2 * MT);
  int*   mode_ws     = (int*)  (ws + HIDW + ATT + PK + PART + 3 * MT);

  prep_kernel<<<641, 256, 0, stream>>>(inp, Wl, bl, hid_ws, Wc, pk, mask, mode_ws);
  att_gemm_kernel<<<dim3(NCH_, B_), 256, 0, stream>>>(
      context, pk, hid_ws, bc, V, mask, mode_ws, att_ws, partial, mt, lt);
  finalize_kernel<<<B_, 256, 0, stream>>>(mask, att_ws, mode_ws, mt, lt, sc, alpha);
  hiddendot_kernel<<<dim3(HID_ / 64, B_), 256, 0, stream>>>(Wc, bc, partial, sc, hidden);
}

// Round 6
// 460.676 us; speedup vs baseline: 1.2162x; 1.0400x over previous
//
#include <hip/hip_runtime.h>
#include <hip/hip_bf16.h>
#include <cstdint>
#include <cstddef>

// Problem constants (B, S, INP, HID) from the reference
#define B_   64
#define S_   2048
#define INP_ 512
#define HID_ 512
#define STILE 64         // s-rows per att_gemm block
#define NCH_ 32          // s-tiles per row (= S_/STILE = att_gemm grid.x)

typedef float          floatx4  __attribute__((ext_vector_type(4)));
typedef __bf16         bf16x8   __attribute__((ext_vector_type(8)));
typedef unsigned short ushortx8 __attribute__((ext_vector_type(8)));
typedef unsigned short ushortx4 __attribute__((ext_vector_type(4)));

#define K2E 1.4426950408889634f

__device__ __forceinline__ unsigned short f2bf(float f) {
  unsigned u = __float_as_uint(f);
  u += 0x7FFFu + ((u >> 16) & 1u);          // round-to-nearest-even
  return (unsigned short)(u >> 16);
}
__device__ __forceinline__ float bf2f(unsigned short h) {
  return __uint_as_float(((unsigned)h) << 16);
}
// tanh(x) = 1 - 2/(exp(2x)+1); exp(2x) = exp2(x * 2*log2(e)).  ~1e-6 accuracy, inf-safe.
__device__ __forceinline__ float fast_tanh(float x) {
  float u = __builtin_amdgcn_exp2f(x * 2.88539008177792681472f);
  return 1.0f - 2.0f * __builtin_amdgcn_rcpf(u + 1.0f);
}

__device__ __forceinline__ bool mask_at(const void* mask, int mode, size_t idx) {
  if (mode == 0) return ((const int*)mask)[idx] != 0;
  if (mode == 1) return ((const float*)mask)[idx] != 0.0f;
  return ((const unsigned char*)mask)[idx] != 0;
}

// ---------------------------------------------------------------------------
// prep: blocks [0,128): pack Wc -> bf16 MFMA A-fragment order.
//       blocks [128,640): hid[b,h] = inp[b,:]·Wl[h,:] + bl[h].
//       block 640: mask-encoding autodetect -> mode_ws.
// pk[(m16*1024 + ks*64 + lane)*8 + j] = Wc[m16*16 + (lane&15)][ks*32 + (lane>>4)*8 + j]
// ---------------------------------------------------------------------------
__global__ __launch_bounds__(256) void prep_kernel(
    const float* __restrict__ inp, const float* __restrict__ Wl,
    const float* __restrict__ bl, float* __restrict__ hid,
    const float* __restrict__ Wc, unsigned short* __restrict__ pk,
    const void* __restrict__ mask, int* __restrict__ mode_ws)
{
  __shared__ float vs[512];
  __shared__ int flags;
  const int t = threadIdx.x;
  if (blockIdx.x == 640) {
    if (t == 0) flags = 0;
    __syncthreads();
    int f = 0;
    const unsigned* mw = (const unsigned*)mask;
    for (int i = t; i < 512; i += 256) {
      unsigned v = mw[i];
      if (v > 1u) f |= 1;
      if (v != 0u && v != 0x3f800000u) f |= 2;
    }
    if (f) atomicOr(&flags, f);
    __syncthreads();
    if (t == 0) {
      const int fl = flags;
      *mode_ws = ((fl & 1) == 0) ? 0 : (((fl & 2) == 0) ? 1 : 2);
    }
    return;
  }
  if (blockIdx.x < 128) {
    int g = blockIdx.x * 256 + t;               // 32768 threads
    int l = g & 63, ks = (g >> 6) & 15, m16 = g >> 10;
    int row = m16 * 16 + (l & 15);
    int kb  = ks * 32 + (l >> 4) * 8;
    const float4* s = (const float4*)(Wc + (size_t)row * 512 + kb);
    float4 a = s[0], c = s[1];
    ushortx8 o = { f2bf(a.x), f2bf(a.y), f2bf(a.z), f2bf(a.w),
                   f2bf(c.x), f2bf(c.y), f2bf(c.z), f2bf(c.w) };
    *(ushortx8*)(pk + (size_t)g * 8) = o;
    return;
  }
  const int bx = blockIdx.x - 128;              // 0..511
  const int xo = bx & 7, b = bx >> 3;
  const int w = t >> 6, lane = t & 63;
  for (int i = t; i < 512; i += 256) vs[i] = inp[(size_t)b * 512 + i];
  __syncthreads();
  float vl[8];
  #pragma unroll
  for (int j = 0; j < 8; ++j) vl[j] = vs[lane * 8 + j];
  const int h0 = xo * 64 + w * 16;
  #pragma unroll
  for (int i = 0; i < 16; ++i) {
    const int h = h0 + i;
    const float4* wr = (const float4*)(Wl + (size_t)h * 512 + lane * 8);
    float4 w0 = wr[0], w1 = wr[1];
    float d = w0.x*vl[0] + w0.y*vl[1] + w0.z*vl[2] + w0.w*vl[3]
            + w1.x*vl[4] + w1.y*vl[5] + w1.z*vl[6] + w1.w*vl[7];
    #pragma unroll
    for (int off = 32; off; off >>= 1) d += __shfl_xor(d, off);
    if (lane == 0) hid[(size_t)b * 512 + h] = bl[h] + d;
  }
}

// ---------------------------------------------------------------------------
// att GEMM + tile-softmax partials (flash-style).
// Round-6 restructure: 512 threads, 8 waves x 64 h-rows each -> acc[4][4]
// (64 AGPRs, was 128).  The freed registers implement TRUE T14 pipelining:
//   issue slice p+1 loads (4 float4/thread, named regs)  -> phase start
//   MFMA slice p (4 ksl x 16 MFMA/wave)                  -> covers HBM latency
//   cvt + ds_write slice p+1 (vmcnt wait lands HERE)     -> after the MFMAs
//   one barrier
// Phase column-slices of the persistent [64][512] tile are disjoint, so no
// WAR barrier is needed between staging and compute.
// ---------------------------------------------------------------------------
__global__ __launch_bounds__(512, 2) void att_gemm_kernel(
    const float* __restrict__ context, const unsigned short* __restrict__ Wc_pk,
    const float* __restrict__ hid, const float* __restrict__ bc,
    const float* __restrict__ V, const void* __restrict__ mask,
    const int* __restrict__ mode_ws,
    float* __restrict__ att, float* __restrict__ partial,
    float* __restrict__ mt, float* __restrict__ lt)
{
  // full context tile: 64 s-rows x 512 k (bf16), per-128-col-slice XOR swizzle
  __shared__ alignas(16) unsigned short bsm[STILE * 512];   // 64 KB
  __shared__ float hid_sm[512];
  __shared__ float V_sm[512];
  __shared__ float bc_sm[512];
  __shared__ float att_sm[STILE];
  __shared__ float w_sm[STILE];

  const int b    = blockIdx.y;
  const int c    = blockIdx.x;
  const int s0   = c * STILE;
  const int t    = threadIdx.x;
  const int lane = t & 63;
  const int w    = t >> 6;          // wave id 0..7: h-rows [w*64, w*64+64)
  const int quad = lane >> 4;
  const int l15  = lane & 15;

  const int mode = *mode_ws;        // uniform scalar (prep_kernel wrote it)

  for (int i = t; i < 512; i += 512) {
    hid_sm[i] = hid[b * 512 + i];
    V_sm[i]   = V[i];
    bc_sm[i]  = bc[i];
  }
  if (t < STILE) att_sm[t] = 0.0f;

  floatx4 acc[4][4];
  #pragma unroll
  for (int m = 0; m < 4; ++m)
    #pragma unroll
    for (int n = 0; n < 4; ++n) { floatx4 z = {0.f,0.f,0.f,0.f}; acc[m][n] = z; }

  const unsigned short* apBase = Wc_pk + (size_t)(w * 4) * 8192 + lane * 8;
  const float* src = context + ((size_t)b * S_ + s0) * INP_;

  // staging geometry: 512 threads x 4 float4 per 64x128 slice.
  // chunk id = t + i*512 -> row = (t>>5) + 16*i, c4 = t&31 (row&7 invariant).
  const int rb   = t >> 5;                 // base row 0..15
  const int c4   = t & 31;
  const int sw   = (c4 >> 1) ^ (rb & 7);   // swizzled chunk (thread-invariant)
  const int dst_off = sw * 8 + (c4 & 1) * 4;

  // ---- prologue: stage slice 0 synchronously
  {
    const float* sp = src + c4 * 4;
    float4 f0 = *(const float4*)(sp + (size_t)(rb     ) * INP_);
    float4 f1 = *(const float4*)(sp + (size_t)(rb + 16) * INP_);
    float4 f2 = *(const float4*)(sp + (size_t)(rb + 32) * INP_);
    float4 f3 = *(const float4*)(sp + (size_t)(rb + 48) * INP_);
    ushortx4 h0 = { f2bf(f0.x), f2bf(f0.y), f2bf(f0.z), f2bf(f0.w) };
    ushortx4 h1 = { f2bf(f1.x), f2bf(f1.y), f2bf(f1.z), f2bf(f1.w) };
    ushortx4 h2 = { f2bf(f2.x), f2bf(f2.y), f2bf(f2.z), f2bf(f2.w) };
    ushortx4 h3 = { f2bf(f3.x), f2bf(f3.y), f2bf(f3.z), f2bf(f3.w) };
    *(ushortx4*)(&bsm[(rb     ) * 512 + dst_off]) = h0;
    *(ushortx4*)(&bsm[(rb + 16) * 512 + dst_off]) = h1;
    *(ushortx4*)(&bsm[(rb + 32) * 512 + dst_off]) = h2;
    *(ushortx4*)(&bsm[(rb + 48) * 512 + dst_off]) = h3;
  }
  __syncthreads();                            // slice 0 + params visible

  for (int phase = 0; phase < 4; ++phase) {
    // T14 issue-early: loads for slice p+1 (16 VGPRs live across the MFMAs)
    float4 n0, n1, n2, n3;
    if (phase < 3) {
      const float* sp = src + (phase + 1) * 128 + c4 * 4;
      n0 = *(const float4*)(sp + (size_t)(rb     ) * INP_);
      n1 = *(const float4*)(sp + (size_t)(rb + 16) * INP_);
      n2 = *(const float4*)(sp + (size_t)(rb + 32) * INP_);
      n3 = *(const float4*)(sp + (size_t)(rb + 48) * INP_);
    }
    // MFMA on slice `phase`
    #pragma unroll
    for (int ksl = 0; ksl < 4; ++ksl) {
      const int ksg = phase * 4 + ksl;
      bf16x8 af[4];
      #pragma unroll
      for (int m = 0; m < 4; ++m)
        af[m] = *(const bf16x8*)(apBase + (size_t)m * 8192 + ksg * 512);
      bf16x8 bfr[4];
      #pragma unroll
      for (int n = 0; n < 4; ++n) {
        int row = n * 16 + l15;
        int cc  = ksl * 4 + quad;
        bfr[n] = *(const bf16x8*)(&bsm[row * 512 + phase * 128 + ((cc ^ (row & 7)) * 8)]);
      }
      __builtin_amdgcn_s_setprio(1);
      #pragma unroll
      for (int m = 0; m < 4; ++m)
        #pragma unroll
        for (int n = 0; n < 4; ++n)
          acc[m][n] = __builtin_amdgcn_mfma_f32_16x16x32_bf16(af[m], bfr[n], acc[m][n], 0, 0, 0);
      __builtin_amdgcn_s_setprio(0);
    }
    // T14 write-late: the vmcnt wait for n0..n3 lands here, after the MFMAs
    if (phase < 3) {
      ushortx4 h0 = { f2bf(n0.x), f2bf(n0.y), f2bf(n0.z), f2bf(n0.w) };
      ushortx4 h1 = { f2bf(n1.x), f2bf(n1.y), f2bf(n1.z), f2bf(n1.w) };
      ushortx4 h2 = { f2bf(n2.x), f2bf(n2.y), f2bf(n2.z), f2bf(n2.w) };
      ushortx4 h3 = { f2bf(n3.x), f2bf(n3.y), f2bf(n3.z), f2bf(n3.w) };
      unsigned short* dp = &bsm[(phase + 1) * 128 + dst_off];
      *(ushortx4*)(dp + (size_t)(rb     ) * 512) = h0;
      *(ushortx4*)(dp + (size_t)(rb + 16) * 512) = h1;
      *(ushortx4*)(dp + (size_t)(rb + 32) * 512) = h2;
      *(ushortx4*)(dp + (size_t)(rb + 48) * 512) = h3;
    }
    __syncthreads();                          // slice p+1 visible next iter
  }

  // ---- att epilogue.  C/D layout (m89-verified): col(s)=lane&15, row(h)=quad*4+reg.
  float attacc[4] = {0.f, 0.f, 0.f, 0.f};
  #pragma unroll
  for (int m = 0; m < 4; ++m) {
    const int hb = w * 64 + m * 16 + quad * 4;
    #pragma unroll
    for (int r = 0; r < 4; ++r) {
      const int h = hb + r;
      const float base = hid_sm[h] + bc_sm[h];
      const float vv = V_sm[h];
      #pragma unroll
      for (int n = 0; n < 4; ++n)
        attacc[n] += vv * fast_tanh(base + acc[m][n][r]);
    }
  }
  #pragma unroll
  for (int n = 0; n < 4; ++n) {
    float v = attacc[n];
    v += __shfl_xor(v, 16);
    v += __shfl_xor(v, 32);
    if (lane < 16) atomicAdd(&att_sm[n * 16 + l15], v);
  }
  __syncthreads();

  // ---- tile softmax: m_c, w_s, l_c (threads 0..63 = wave 0)
  if (t < STILE) {
    att[(size_t)b * S_ + s0 + t] = att_sm[t];
    const bool m = mask_at(mask, mode, (size_t)b * S_ + s0 + t);
    const float av = att_sm[t];
    float mv = m ? -1e30f : av;
    #pragma unroll
    for (int off = 32; off; off >>= 1) mv = fmaxf(mv, __shfl_xor(mv, off));
    const float wv = m ? 0.0f : __builtin_amdgcn_exp2f((av - mv) * K2E);
    w_sm[t] = wv;
    float lv = wv;
    #pragma unroll
    for (int off = 32; off; off >>= 1) lv += __shfl_xor(lv, off);
    if (t == 0) { mt[b * NCH_ + c] = mv; lt[b * NCH_ + c] = lv; }
  }
  __syncthreads();

  // ---- weighted tile reduction: partial_c[k] = sum_s w_s * ctx_tile[s,k]
  // threads 0..255 own k = {2t, 2t+1}; LDS index = unswizzled ^ ((s&7)<<3).
  if (t < 256) {
    const int k0 = t * 2;
    const int p  = k0 >> 7, kl = k0 & 127;
    const int cc = kl >> 2, j = kl & 3;
    const int idxu = p * 128 + (cc >> 1) * 8 + (cc & 1) * 4 + j;
    float ax = 0.f, ay = 0.f;
    #pragma unroll 8
    for (int s = 0; s < STILE; ++s) {
      const unsigned v = *(const unsigned*)(&bsm[s * 512 + (idxu ^ ((s & 7) << 3))]);
      const float wv = w_sm[s];
      ax = fmaf(wv, bf2f((unsigned short)(v & 0xffffu)), ax);
      ay = fmaf(wv, bf2f((unsigned short)(v >> 16)), ay);
    }
    float2 o; o.x = ax; o.y = ay;
    *(float2*)(partial + ((size_t)c * B_ + b) * INP_ + k0) = o;
  }
}

// ---------------------------------------------------------------------------
// hidden + finalize (fused): per (x,b) block recompute (M,L) from the 32
// tile (m_c,l_c); block x==0 also writes alpha.  Then
// hidden[b,h] = bc[h] + Wc[h,:]·cbar[b,:], cbar = sum_c sc_c*partial[c][b].
// ---------------------------------------------------------------------------
__global__ __launch_bounds__(256) void hiddendot_kernel(
    const float* __restrict__ Wc, const float* __restrict__ bc,
    const float* __restrict__ partial,
    const float* __restrict__ mt, const float* __restrict__ lt,
    const float* __restrict__ att, const void* __restrict__ mask,
    const int* __restrict__ mode_ws,
    float* __restrict__ hidden, float* __restrict__ alpha)
{
  __shared__ float vs[512];
  __shared__ float scs[NCH_];
  __shared__ float Msh, Lsh;
  const int b = blockIdx.y, t = threadIdx.x;
  const int w = t >> 6, lane = t & 63;

  if (t < NCH_) {                               // NCH_=32: reduce in lanes 0..31
    float m = mt[b * NCH_ + t];
    #pragma unroll
    for (int off = 16; off; off >>= 1) m = fmaxf(m, __shfl_xor(m, off));
    float e = __builtin_amdgcn_exp2f((mt[b * NCH_ + t] - m) * K2E) * lt[b * NCH_ + t];
    #pragma unroll
    for (int off = 16; off; off >>= 1) e += __shfl_xor(e, off);
    if (t == 0) { Msh = m; Lsh = e; }
  }
  __syncthreads();
  const float M = Msh;
  const float rL = 1.0f / Lsh;
  if (t < NCH_) scs[t] = __builtin_amdgcn_exp2f((mt[b * NCH_ + t] - M) * K2E) * rL;

  if (blockIdx.x == 0) {                        // one block per b writes alpha
    const int mode = *mode_ws;
    #pragma unroll
    for (int i = 0; i < 8; ++i) {
      const int idx = i * 256 + t;
      const bool m = mask_at(mask, mode, (size_t)b * S_ + idx);
      const float a = m ? 0.0f
                        : __builtin_amdgcn_exp2f((att[(size_t)b * S_ + idx] - M) * K2E) * rL;
      alpha[(size_t)b * S_ + idx] = a;
    }
  }
  __syncthreads();                              // scs visible

  for (int i = t; i < 512; i += 256) {
    float s = 0.0f;
    #pragma unroll 4
    for (int c = 0; c < NCH_; ++c)
      s += scs[c] * partial[((size_t)c * B_ + b) * INP_ + i];
    vs[i] = s;
  }
  __syncthreads();
  float vl[8];
  #pragma unroll
  for (int j = 0; j < 8; ++j) vl[j] = vs[lane * 8 + j];
  const int h0 = blockIdx.x * 64 + w * 16;
  #pragma unroll
  for (int i = 0; i < 16; ++i) {
    const int h = h0 + i;
    const float4* wr = (const float4*)(Wc + (size_t)h * 512 + lane * 8);
    float4 w0 = wr[0], w1 = wr[1];
    float d = w0.x*vl[0] + w0.y*vl[1] + w0.z*vl[2] + w0.w*vl[3]
            + w1.x*vl[4] + w1.y*vl[5] + w1.z*vl[6] + w1.w*vl[7];
    #pragma unroll
    for (int off = 32; off; off >>= 1) d += __shfl_xor(d, off);
    if (lane == 0) hidden[(size_t)b * 512 + h] = bc[h] + d;
  }
}

// ---------------------------------------------------------------------------
extern "C" void kernel_launch(void* const* d_in, const int* in_sizes, int n_in,
                              void* d_out, int out_size, void* d_ws, size_t ws_size,
                              hipStream_t stream)
{
  const float* inp     = (const float*)d_in[0];
  const float* context = (const float*)d_in[1];
  const void*  mask    = d_in[2];
  const float* Wl      = (const float*)d_in[3];
  const float* bl      = (const float*)d_in[4];
  const float* Wc      = (const float*)d_in[5];
  const float* bc      = (const float*)d_in[6];
  const float* V       = (const float*)d_in[7];

  float* hidden = (float*)d_out;                 // [B, HID]
  float* alpha  = (float*)d_out + B_ * HID_;     // [B, S]

  char* ws = (char*)d_ws;
  const size_t HIDW = (size_t)B_ * HID_ * 4;           // 128 KB
  const size_t ATT  = (size_t)B_ * S_ * 4;             // 512 KB
  const size_t PK   = (size_t)HID_ * INP_ * 2;         // 512 KB
  const size_t PART = (size_t)NCH_ * B_ * INP_ * 4;    // 4 MB
  const size_t MT   = (size_t)B_ * NCH_ * 4;           // 8 KB

  float* hid_ws      = (float*)ws;
  float* att_ws      = (float*)(ws + HIDW);
  unsigned short* pk = (unsigned short*)(ws + HIDW + ATT);
  float* partial     = (float*)(ws + HIDW + ATT + PK);
  float* mt          = (float*)(ws + HIDW + ATT + PK + PART);
  float* lt          = (float*)(ws + HIDW + ATT + PK + PART + MT);
  int*   mode_ws     = (int*)  (ws + HIDW + ATT + PK + PART + 2 * MT);

  prep_kernel<<<641, 256, 0, stream>>>(inp, Wl, bl, hid_ws, Wc, pk, mask, mode_ws);
  att_gemm_kernel<<<dim3(NCH_, B_), 512, 0, stream>>>(
      context, pk, hid_ws, bc, V, mask, mode_ws, att_ws, partial, mt, lt);
  hiddendot_kernel<<<dim3(HID_ / 64, B_), 256, 0, stream>>>(
      Wc, bc, partial, mt, lt, att_ws, mask, mode_ws, hidden, alpha);
}